// Round 13
// baseline (625.640 us; speedup 1.0000x reference)
//
#include <hip/hip_runtime.h>

// GAT 3-layer (N=50000, E=800000 (+N self loops), H=2, C=64, widths 128)
// Round 13: R10 baseline (best: 339.8us) + degree-sorted node order for
// fused_agg (bucket sort by degree, descending; equalizes per-block wave
// durations -- Poisson(17) degrees made blocks wait on their slowest wave).
// bn_fin zeroes part[] after consuming (drops 2 in-loop memsets).
// R12's LDS-staged gemm and partitioned scatter reverted (net -13us).

#define N_NODES 50000
#define N_EDGES 800000
#define ET (N_EDGES + N_NODES)   // 850000 incl self loops
#define FDIM 128
#define SLOPE 0.2f
#define BN_EPS 1e-5f
#define SCAN_NB 196              // ceil(50000/256)
#define LOG2E 1.44269504088896340736f
#define WSTRIDE 18432            // 9 tiles * 4 ks * 64 lanes * 8

typedef __attribute__((ext_vector_type(8))) short bf16x8;
typedef __attribute__((ext_vector_type(4))) float f32x4;
typedef __attribute__((ext_vector_type(8))) unsigned short u16x8;

__device__ __forceinline__ unsigned short f2bf(float f) {
  unsigned u = __float_as_uint(f);
  u = u + 0x7fffu + ((u >> 16) & 1u);   // RNE
  return (unsigned short)(u >> 16);
}
__device__ __forceinline__ unsigned packbf(float lo, float hi) {
  return ((unsigned)f2bf(hi) << 16) | (unsigned)f2bf(lo);
}
__device__ __forceinline__ float bflo(unsigned p) { return __uint_as_float(p << 16); }
__device__ __forceinline__ float bfhi(unsigned p) { return __uint_as_float(p & 0xffff0000u); }

// ---------------- CSR build (rank-based, atomic-free scatter) ----------------

__global__ __launch_bounds__(256) void hist_rank(const int* __restrict__ dst,
                                                 int* __restrict__ counts,
                                                 int* __restrict__ rank) {
  int i = blockIdx.x * 256 + threadIdx.x;
  if (i >= ET) return;
  int d = (i < N_EDGES) ? dst[i] : i - N_EDGES;
  rank[i] = atomicAdd(&counts[d], 1);
}

__global__ __launch_bounds__(256) void scan_blk(const int* __restrict__ counts,
                                                int* __restrict__ rowptr,
                                                int* __restrict__ partials) {
  int i = blockIdx.x * 256 + threadIdx.x;
  int lane = threadIdx.x & 63, wv = threadIdx.x >> 6;
  int c = (i < N_NODES) ? counts[i] : 0;
  int v = c;
#pragma unroll
  for (int off = 1; off < 64; off <<= 1) {
    int u = __shfl_up(v, off);
    if (lane >= off) v += u;
  }
  __shared__ int wsum[4];
  if (lane == 63) wsum[wv] = v;
  __syncthreads();
  int add = 0;
  for (int w = 0; w < wv; ++w) add += wsum[w];
  if (i < N_NODES) rowptr[i] = v - c + add;
  if (threadIdx.x == 255) partials[blockIdx.x] = add + v;
}

// final pass: each block reduces partials[0..blockIdx) inline (196 values)
__global__ __launch_bounds__(256) void scan_fin(int* __restrict__ rowptr,
                                                const int* __restrict__ partials) {
  __shared__ int sh[256];
  int t = threadIdx.x;
  sh[t] = (t < (int)blockIdx.x && t < SCAN_NB) ? partials[t] : 0;
  __syncthreads();
#pragma unroll
  for (int off = 128; off > 0; off >>= 1) {
    if (t < off) sh[t] += sh[t + off];
    __syncthreads();
  }
  int base = sh[0];
  int i = blockIdx.x * 256 + t;
  if (i < N_NODES) rowptr[i] += base;
  if (i == 0) rowptr[N_NODES] = ET;
}

__global__ __launch_bounds__(256) void scatter_pos(const int* __restrict__ src,
                                                   const int* __restrict__ dst,
                                                   const int* __restrict__ rowptr,
                                                   const int* __restrict__ rank,
                                                   int* __restrict__ csr_src) {
  int i = blockIdx.x * 256 + threadIdx.x;
  if (i >= ET) return;
  int d, s;
  if (i < N_EDGES) { d = dst[i]; s = src[i]; } else { d = s = i - N_EDGES; }
  csr_src[rowptr[d] + rank[i]] = s;
}

// ---------------- degree bucket-sort (descending) ----------------
__global__ __launch_bounds__(256) void deg_hist(const int* __restrict__ counts,
                                                int* __restrict__ dh) {
  int i = blockIdx.x * 256 + threadIdx.x;
  if (i >= N_NODES) return;
  int d = counts[i]; if (d > 255) d = 255;
  atomicAdd(&dh[d], 1);
}

// offsets for DESCENDING degree: off[d] = # nodes with degree > d
__global__ __launch_bounds__(256) void deg_scan(const int* __restrict__ dh,
                                                int* __restrict__ dfill) {
  __shared__ int sh[256];
  int t = threadIdx.x;
  sh[t] = dh[t];
  __syncthreads();
  int off = 0;
  for (int d = t + 1; d < 256; ++d) off += sh[d];
  dfill[t] = off;
}

__global__ __launch_bounds__(256) void deg_scat(const int* __restrict__ counts,
                                                int* __restrict__ dfill,
                                                int* __restrict__ order) {
  int i = blockIdx.x * 256 + threadIdx.x;
  if (i >= N_NODES) return;
  int d = counts[i]; if (d > 255) d = 255;
  int pos = atomicAdd(&dfill[d], 1);
  order[pos] = i;
}

// ---------------- W repack: B-fragment order + 4 logit columns (tile 8) ----
__global__ __launch_bounds__(256) void repack_w(const float* __restrict__ W0,
                                                const float* __restrict__ W1,
                                                const float* __restrict__ W2,
                                                const float* __restrict__ as0,
                                                const float* __restrict__ as1,
                                                const float* __restrict__ as2,
                                                const float* __restrict__ ad0,
                                                const float* __restrict__ ad1,
                                                const float* __restrict__ ad2,
                                                unsigned short* __restrict__ Wr) {
  int i = blockIdx.x * 256 + threadIdx.x;
  if (i >= 3 * WSTRIDE) return;
  int L = i / WSTRIDE, rem = i % WSTRIDE;
  int t  = rem >> 11;
  int ks = (rem >> 9) & 3;
  int ln = (rem >> 3) & 63;
  int j  = rem & 7;
  int k  = ks * 32 + (ln >> 4) * 8 + j;
  const float* W = (L == 0) ? W0 : ((L == 1) ? W1 : W2);
  float val;
  if (t < 8) {
    int col = t * 16 + (ln & 15);
    val = W[k * 128 + col];
  } else {
    int cl = ln & 15;
    if (cl < 4) {
      int head = cl & 1;
      const float* a = (cl < 2) ? ((L == 0) ? as0 : (L == 1) ? as1 : as2)
                                : ((L == 0) ? ad0 : (L == 1) ? ad1 : ad2);
      float s = 0.f;
      const float* wrow = W + k * 128 + head * 64;
      const float* ah = a + head * 64;
#pragma unroll 8
      for (int c = 0; c < 64; ++c) s = fmaf(wrow[c], ah[c], s);
      val = s * LOG2E;
    } else {
      val = 0.f;
    }
  }
  Wr[i] = f2bf(val);
}

// ---------------- BN finalize: part[32][256] -> lsbuf[256]; zero part ------
__global__ __launch_bounds__(128) void bn_fin(float* __restrict__ part,
                                              const float* __restrict__ g,
                                              const float* __restrict__ be,
                                              float* __restrict__ lsbuf) {
  int t = threadIdx.x;   // 0..127
  float s = 0.f, q = 0.f;
#pragma unroll
  for (int k = 0; k < 32; ++k) {
    s += part[k * 256 + t];
    q += part[k * 256 + 128 + t];
    part[k * 256 + t] = 0.f;
    part[k * 256 + 128 + t] = 0.f;
  }
  float mu  = s * (1.f / N_NODES);
  float var = q * (1.f / N_NODES) - mu * mu;
  float sc  = rsqrtf(var + BN_EPS) * g[t];
  lsbuf[t]       = sc;
  lsbuf[128 + t] = be[t] - mu * sc;
}

// ---------------- MFMA gemm (9 tiles: 8 H cols + logit cols) — R10 form ----
__global__ __launch_bounds__(256) void gemm_mfma(const void* __restrict__ Xin,
                                                 const unsigned short* __restrict__ WrL,
                                                 const float* __restrict__ lsbuf,
                                                 unsigned short* __restrict__ Hbf,
                                                 float* __restrict__ als,
                                                 float* __restrict__ ald,
                                                 int inBF) {
  __shared__ unsigned short lds[4][16][128];
  __shared__ float ls_scale[128], ls_shift[128];
  int lane = threadIdx.x & 63;
  int wv   = threadIdx.x >> 6;

  if (inBF) {
    int t = threadIdx.x;
    if (t < 128) {
      ls_scale[t] = lsbuf[t];
      ls_shift[t] = lsbuf[128 + t];
    }
    __syncthreads();
  }

  int row0 = blockIdx.x * 64 + wv * 16;
  int gidx = lane & 15;
  int quad = lane >> 4;
  int rA   = row0 + gidx;
  int rAc  = rA < N_NODES ? rA : N_NODES - 1;
  int koff = quad * 8;

  f32x4 acc[9] = {};
#pragma unroll
  for (int ks = 0; ks < 4; ++ks) {
    int cb = ks * 32 + koff;
    float xv[8];
    if (inBF) {
      const uint4* xr = (const uint4*)((const unsigned*)Xin + (size_t)rAc * 64 + (cb >> 1));
      uint4 xa = *xr;
      xv[0] = bflo(xa.x); xv[1] = bfhi(xa.x);
      xv[2] = bflo(xa.y); xv[3] = bfhi(xa.y);
      xv[4] = bflo(xa.z); xv[5] = bfhi(xa.z);
      xv[6] = bflo(xa.w); xv[7] = bfhi(xa.w);
    } else {
      const float4* xr = (const float4*)((const float*)Xin + (size_t)rAc * FDIM + cb);
      float4 xa = xr[0], xb = xr[1];
      xv[0] = xa.x; xv[1] = xa.y; xv[2] = xa.z; xv[3] = xa.w;
      xv[4] = xb.x; xv[5] = xb.y; xv[6] = xb.z; xv[7] = xb.w;
    }
    bf16x8 afrag;
    if (inBF) {
#pragma unroll
      for (int j = 0; j < 8; ++j) {
        int c = cb + j;
        float v = fmaf(xv[j], ls_scale[c], ls_shift[c]);
        v = v > 0.f ? v : 0.f;
        afrag[j] = (short)f2bf(v);
      }
    } else {
#pragma unroll
      for (int j = 0; j < 8; ++j) afrag[j] = (short)f2bf(xv[j]);
    }
#pragma unroll
    for (int t = 0; t < 9; ++t) {
      bf16x8 bfrag = *(const bf16x8*)(WrL + ((size_t)((t * 4 + ks) * 64 + lane)) * 8);
      acc[t] = __builtin_amdgcn_mfma_f32_16x16x32_bf16(afrag, bfrag, acc[t], 0, 0, 0);
    }
  }

  // ---- logit columns: lane (quad,gidx<4) holds al[row=quad*4+r][gidx] ----
  if (gidx < 4) {
    float* dp = (gidx < 2) ? als : ald;
    int hd = gidx & 1;
#pragma unroll
    for (int r = 0; r < 4; ++r) {
      int row = row0 + quad * 4 + r;
      if (row < N_NODES) dp[row * 2 + hd] = acc[8][r];
    }
  }

  // ---- bf16 H store via LDS transpose ----
#pragma unroll
  for (int t = 0; t < 8; ++t)
#pragma unroll
    for (int r = 0; r < 4; ++r)
      lds[wv][quad * 4 + r][t * 16 + gidx] = f2bf(acc[t][r]);
  __syncthreads();
#pragma unroll
  for (int it = 0; it < 4; ++it) {
    int rloc = it * 4 + quad;
    int row = row0 + rloc;
    if (row < N_NODES)
      *(u16x8*)(Hbf + (size_t)row * FDIM + gidx * 8) = *(u16x8*)&lds[wv][rloc][gidx * 8];
  }
}

// ---------------- fused softmax-aggregate (R10 form + degree order) --------
// One wave per sorted node (order[] descending degree). Lane owns channels
// 2l,2l+1; lanes 0-31 = head 0, 32-63 = head 1. exp2 logits, no max shift.
// 8-deep clamped register prefetch. mode 0: write Abf bf16-pair + BN sums;
// mode 2: head-mean + b2 -> out fp32 [N,64].
__global__ __launch_bounds__(256) void fused_agg(const int* __restrict__ order,
                                                 const int* __restrict__ rowptr,
                                                 const int* __restrict__ csr_src,
                                                 const unsigned* __restrict__ H2,
                                                 const float* __restrict__ als,
                                                 const float* __restrict__ ald,
                                                 unsigned* __restrict__ Abf,
                                                 float* __restrict__ out,
                                                 const float* __restrict__ b2,
                                                 float* __restrict__ part,
                                                 int mode) {
  int lane = threadIdx.x & 63;
  bool hi = lane >= 32;
  int wid = (blockIdx.x * 256 + threadIdx.x) >> 6;
  int n = __builtin_amdgcn_readfirstlane(order[wid]);
  int beg = rowptr[n], end = rowptr[n + 1];
  float2 adv = ((const float2*)ald)[n];
  float advh = hi ? adv.y : adv.x;

  int b0 = end - 8; if (b0 > beg) b0 = beg; if (b0 < 0) b0 = 0;
  int delta = beg - b0;
  int sa[8]; float2 aa[8]; unsigned ha[8];
#pragma unroll
  for (int i = 0; i < 8; ++i) sa[i] = csr_src[b0 + i];
#pragma unroll
  for (int i = 0; i < 8; ++i) {
    aa[i] = ((const float2*)als)[sa[i]];
    ha[i] = H2[(size_t)sa[i] * 64 + lane];
  }

  float l = 0.f, ox = 0.f, oy = 0.f;

#define STEP(i) { \
    float v_ = (hi ? aa[i].y : aa[i].x) + advh; \
    v_ = fmaxf(v_, SLOPE * v_); \
    float e_ = exp2f(v_); \
    l += e_; \
    ox = fmaf(e_, bflo(ha[i]), ox); \
    oy = fmaf(e_, bfhi(ha[i]), oy); }

  int j = beg;
  for (; j + 8 <= end; j += 8) {
    int pp = j + 8; if (pp > end - 8) pp = end - 8;   // end-8 >= beg here
    int sn[8]; float2 an[8]; unsigned hn[8];
#pragma unroll
    for (int i = 0; i < 8; ++i) sn[i] = csr_src[pp + i];
#pragma unroll
    for (int i = 0; i < 8; ++i) {
      an[i] = ((const float2*)als)[sn[i]];
      hn[i] = H2[(size_t)sn[i] * 64 + lane];
    }
    STEP(0); STEP(1); STEP(2); STEP(3); STEP(4); STEP(5); STEP(6); STEP(7);
    delta = j + 8 - pp;
#pragma unroll
    for (int i = 0; i < 8; ++i) { aa[i] = an[i]; ha[i] = hn[i]; }
  }
  int rem = end - j;
  int hik = delta + rem;
  if (0 >= delta && 0 < hik) STEP(0);
  if (1 >= delta && 1 < hik) STEP(1);
  if (2 >= delta && 2 < hik) STEP(2);
  if (3 >= delta && 3 < hik) STEP(3);
  if (4 >= delta && 4 < hik) STEP(4);
  if (5 >= delta && 5 < hik) STEP(5);
  if (6 >= delta && 6 < hik) STEP(6);
  if (7 >= delta && 7 < hik) STEP(7);
#undef STEP

  float inv = 1.f / (l + 1e-16f);
  ox *= inv; oy *= inv;

  if (mode == 0) {
    Abf[(size_t)n * 64 + lane] = packbf(ox, oy);
    __shared__ float sh[4][4][64];
    int wv = threadIdx.x >> 6;
    sh[wv][0][lane] = ox;
    sh[wv][1][lane] = oy;
    sh[wv][2][lane] = ox * ox;
    sh[wv][3][lane] = oy * oy;
    __syncthreads();
    if (threadIdx.x < 64) {
      int t = threadIdx.x;
      float a0 = 0.f, a1 = 0.f, a2 = 0.f, a3 = 0.f;
#pragma unroll
      for (int w = 0; w < 4; ++w) {
        a0 += sh[w][0][t]; a1 += sh[w][1][t];
        a2 += sh[w][2][t]; a3 += sh[w][3][t];
      }
      float* slot = part + (blockIdx.x & 31) * 256;
      atomicAdd(&slot[2 * t],           a0);
      atomicAdd(&slot[2 * t + 1],       a1);
      atomicAdd(&slot[128 + 2 * t],     a2);
      atomicAdd(&slot[128 + 2 * t + 1], a3);
    }
  } else {
    float px = __shfl_xor(ox, 32);
    float py = __shfl_xor(oy, 32);
    if (lane < 32) {
      int c = lane * 2;
      float2 outv = {0.5f * (ox + px) + b2[c], 0.5f * (oy + py) + b2[c + 1]};
      *(float2*)(out + (size_t)n * 64 + c) = outv;
    }
  }
}

extern "C" void kernel_launch(void* const* d_in, const int* in_sizes, int n_in,
                              void* d_out, int out_size, void* d_ws, size_t ws_size,
                              hipStream_t stream) {
  const float* x  = (const float*)d_in[0];
  const int*   ei = (const int*)d_in[1];
  const int* src = ei;
  const int* dst = ei + N_EDGES;

  const float* W[3]    = {(const float*)d_in[2],  (const float*)d_in[8],  (const float*)d_in[14]};
  const float* asrc[3] = {(const float*)d_in[3],  (const float*)d_in[9],  (const float*)d_in[15]};
  const float* adst[3] = {(const float*)d_in[4],  (const float*)d_in[10], (const float*)d_in[16]};
  const float* g[2]    = {(const float*)d_in[6],  (const float*)d_in[12]};
  const float* be[2]   = {(const float*)d_in[7],  (const float*)d_in[13]};
  const float* b2      = (const float*)d_in[17];

  // workspace (4-byte units, regions 16B-aligned):
  int*   counts   = (int*)d_ws;
  int*   rowptr   = counts + 50048;
  int*   partials = rowptr + 50048;
  int*   rank     = partials + 256;
  int*   csr_src  = rank + 850048;
  int*   order    = csr_src + 850048;
  int*   dh       = order + 50048;
  int*   dfill    = dh + 256;
  float* part     = (float*)(dfill + 256);       // 32*256 BN partial slots
  float* lsbuf    = part + 8192;                  // 256 scale|shift
  float* als      = lsbuf + 256;
  float* ald      = als + 100096;
  unsigned short* Wr  = (unsigned short*)(ald + 100096);   // 3*WSTRIDE u16
  unsigned short* Hbf = Wr + 3 * WSTRIDE + 128;            // pad to 16B align
  unsigned* Abf   = (unsigned*)(Hbf + (size_t)N_NODES * FDIM);

  // ---- build CSR + degree sort + repack W (all layer-invariant) ----
  hipMemsetAsync(counts, 0, (size_t)N_NODES * sizeof(int), stream);
  hipMemsetAsync(dh, 0, 256 * sizeof(int), stream);
  hipMemsetAsync(part, 0, 8192 * sizeof(float), stream);
  hist_rank<<<(ET + 255) / 256, 256, 0, stream>>>(dst, counts, rank);
  scan_blk<<<SCAN_NB, 256, 0, stream>>>(counts, rowptr, partials);
  scan_fin<<<SCAN_NB, 256, 0, stream>>>(rowptr, partials);
  scatter_pos<<<(ET + 255) / 256, 256, 0, stream>>>(src, dst, rowptr, rank, csr_src);
  deg_hist<<<SCAN_NB, 256, 0, stream>>>(counts, dh);
  deg_scan<<<1, 256, 0, stream>>>(dh, dfill);
  deg_scat<<<SCAN_NB, 256, 0, stream>>>(counts, dfill, order);
  repack_w<<<(3 * WSTRIDE + 255) / 256, 256, 0, stream>>>(
      W[0], W[1], W[2], asrc[0], asrc[1], asrc[2], adst[0], adst[1], adst[2], Wr);

  const int gemm_grid = (N_NODES + 63) / 64;
  const int agg_grid  = N_NODES * 64 / 256;   // 12500, exact (one wave/node)

  for (int L = 0; L < 3; ++L) {
    const void* fin = (L == 0) ? (const void*)x : (const void*)Abf;
    int inBF = (L > 0);
    gemm_mfma<<<gemm_grid, 256, 0, stream>>>(fin, Wr + (size_t)L * WSTRIDE, lsbuf,
                                             Hbf, als, ald, inBF);
    fused_agg<<<agg_grid, 256, 0, stream>>>(order, rowptr, csr_src,
                                            (const unsigned*)Hbf,
                                            als, ald, Abf, (float*)d_out, b2, part,
                                            (L == 2) ? 2 : 0);
    if (L < 2)
      bn_fin<<<1, 128, 0, stream>>>(part, g[L], be[L], lsbuf);
  }
}

// Round 14
// 324.579 us; speedup vs baseline: 1.9275x; 1.9275x over previous
//
#include <hip/hip_runtime.h>

// GAT 3-layer (N=50000, E=800000 (+N self loops), H=2, C=64, widths 128)
// Round 14: revert to R10 structure (best measured: 339.8us). Deltas vs R10,
// all dispatch-count reductions (R13's degree sort removed — deg_hist/deg_scat
// were ~139us each of pure same-address atomic contention, and the ordering
// bought ~0 on fused_agg):
//   1. counts+part adjacent in ws -> single initial memset; bn_fin zeroes
//      part after consuming it (kills the 2 in-loop memsets).
//   2. repack_w folded into hist_rank's launch (block-range split).
// 15 -> 11 dispatches per call.

#define N_NODES 50000
#define N_EDGES 800000
#define ET (N_EDGES + N_NODES)   // 850000 incl self loops
#define FDIM 128
#define SLOPE 0.2f
#define BN_EPS 1e-5f
#define SCAN_NB 196              // ceil(50000/256)
#define HIST_NB 3321             // ceil(ET/256)
#define RPK_NB 216               // ceil(3*WSTRIDE/256)
#define LOG2E 1.44269504088896340736f
#define WSTRIDE 18432            // 9 tiles * 4 ks * 64 lanes * 8

typedef __attribute__((ext_vector_type(8))) short bf16x8;
typedef __attribute__((ext_vector_type(4))) float f32x4;
typedef __attribute__((ext_vector_type(8))) unsigned short u16x8;

__device__ __forceinline__ unsigned short f2bf(float f) {
  unsigned u = __float_as_uint(f);
  u = u + 0x7fffu + ((u >> 16) & 1u);   // RNE
  return (unsigned short)(u >> 16);
}
__device__ __forceinline__ unsigned packbf(float lo, float hi) {
  return ((unsigned)f2bf(hi) << 16) | (unsigned)f2bf(lo);
}
__device__ __forceinline__ float bflo(unsigned p) { return __uint_as_float(p << 16); }
__device__ __forceinline__ float bfhi(unsigned p) { return __uint_as_float(p & 0xffff0000u); }

// ---------------- combined: hist_rank (blocks 0..HIST_NB) + W repack --------
// hist: rank[i] = arrival order of edge i at its dst (spread atomics).
// repack (blocks HIST_NB..): B-fragment-order bf16 W + 4 logit columns
// (tile 8): al = X @ (W*a) with log2e baked in.
__global__ __launch_bounds__(256) void build_pre(const int* __restrict__ dst,
                                                 int* __restrict__ counts,
                                                 int* __restrict__ rank,
                                                 const float* __restrict__ W0,
                                                 const float* __restrict__ W1,
                                                 const float* __restrict__ W2,
                                                 const float* __restrict__ as0,
                                                 const float* __restrict__ as1,
                                                 const float* __restrict__ as2,
                                                 const float* __restrict__ ad0,
                                                 const float* __restrict__ ad1,
                                                 const float* __restrict__ ad2,
                                                 unsigned short* __restrict__ Wr) {
  int bid = blockIdx.x;
  if (bid < HIST_NB) {
    int i = bid * 256 + threadIdx.x;
    if (i >= ET) return;
    int d = (i < N_EDGES) ? dst[i] : i - N_EDGES;
    rank[i] = atomicAdd(&counts[d], 1);
    return;
  }
  int i = (bid - HIST_NB) * 256 + threadIdx.x;
  if (i >= 3 * WSTRIDE) return;
  int L = i / WSTRIDE, rem = i % WSTRIDE;
  int t  = rem >> 11;
  int ks = (rem >> 9) & 3;
  int ln = (rem >> 3) & 63;
  int j  = rem & 7;
  int k  = ks * 32 + (ln >> 4) * 8 + j;
  const float* W = (L == 0) ? W0 : ((L == 1) ? W1 : W2);
  float val;
  if (t < 8) {
    int col = t * 16 + (ln & 15);
    val = W[k * 128 + col];
  } else {
    int cl = ln & 15;
    if (cl < 4) {
      int head = cl & 1;
      const float* a = (cl < 2) ? ((L == 0) ? as0 : (L == 1) ? as1 : as2)
                                : ((L == 0) ? ad0 : (L == 1) ? ad1 : ad2);
      float s = 0.f;
      const float* wrow = W + k * 128 + head * 64;
      const float* ah = a + head * 64;
#pragma unroll 8
      for (int c = 0; c < 64; ++c) s = fmaf(wrow[c], ah[c], s);
      val = s * LOG2E;
    } else {
      val = 0.f;
    }
  }
  Wr[i] = f2bf(val);
}

// ---------------- CSR scan ----------------

__global__ __launch_bounds__(256) void scan_blk(const int* __restrict__ counts,
                                                int* __restrict__ rowptr,
                                                int* __restrict__ partials) {
  int i = blockIdx.x * 256 + threadIdx.x;
  int lane = threadIdx.x & 63, wv = threadIdx.x >> 6;
  int c = (i < N_NODES) ? counts[i] : 0;
  int v = c;
#pragma unroll
  for (int off = 1; off < 64; off <<= 1) {
    int u = __shfl_up(v, off);
    if (lane >= off) v += u;
  }
  __shared__ int wsum[4];
  if (lane == 63) wsum[wv] = v;
  __syncthreads();
  int add = 0;
  for (int w = 0; w < wv; ++w) add += wsum[w];
  if (i < N_NODES) rowptr[i] = v - c + add;
  if (threadIdx.x == 255) partials[blockIdx.x] = add + v;
}

// final pass: each block reduces partials[0..blockIdx) inline (196 values)
__global__ __launch_bounds__(256) void scan_fin(int* __restrict__ rowptr,
                                                const int* __restrict__ partials) {
  __shared__ int sh[256];
  int t = threadIdx.x;
  sh[t] = (t < (int)blockIdx.x && t < SCAN_NB) ? partials[t] : 0;
  __syncthreads();
#pragma unroll
  for (int off = 128; off > 0; off >>= 1) {
    if (t < off) sh[t] += sh[t + off];
    __syncthreads();
  }
  int base = sh[0];
  int i = blockIdx.x * 256 + t;
  if (i < N_NODES) rowptr[i] += base;
  if (i == 0) rowptr[N_NODES] = ET;
}

__global__ __launch_bounds__(256) void scatter_pos(const int* __restrict__ src,
                                                   const int* __restrict__ dst,
                                                   const int* __restrict__ rowptr,
                                                   const int* __restrict__ rank,
                                                   int* __restrict__ csr_src) {
  int i = blockIdx.x * 256 + threadIdx.x;
  if (i >= ET) return;
  int d, s;
  if (i < N_EDGES) { d = dst[i]; s = src[i]; } else { d = s = i - N_EDGES; }
  csr_src[rowptr[d] + rank[i]] = s;
}

// ---------------- BN finalize: part[32][256] -> lsbuf[256]; zero part ------
__global__ __launch_bounds__(128) void bn_fin(float* __restrict__ part,
                                              const float* __restrict__ g,
                                              const float* __restrict__ be,
                                              float* __restrict__ lsbuf) {
  int t = threadIdx.x;   // 0..127
  float s = 0.f, q = 0.f;
#pragma unroll
  for (int k = 0; k < 32; ++k) {
    s += part[k * 256 + t];
    q += part[k * 256 + 128 + t];
    part[k * 256 + t] = 0.f;
    part[k * 256 + 128 + t] = 0.f;
  }
  float mu  = s * (1.f / N_NODES);
  float var = q * (1.f / N_NODES) - mu * mu;
  float sc  = rsqrtf(var + BN_EPS) * g[t];
  lsbuf[t]       = sc;
  lsbuf[128 + t] = be[t] - mu * sc;
}

// ---------------- MFMA gemm (9 tiles: 8 H cols + logit cols) — R10 form ----
// inBF==0: Xin fp32 [N,128], no BN (layer 0).
// inBF==1: Xin bf16-packed u32 [N,64]; BN scale/shift from lsbuf + ReLU.
__global__ __launch_bounds__(256) void gemm_mfma(const void* __restrict__ Xin,
                                                 const unsigned short* __restrict__ WrL,
                                                 const float* __restrict__ lsbuf,
                                                 unsigned short* __restrict__ Hbf,
                                                 float* __restrict__ als,
                                                 float* __restrict__ ald,
                                                 int inBF) {
  __shared__ unsigned short lds[4][16][128];
  __shared__ float ls_scale[128], ls_shift[128];
  int lane = threadIdx.x & 63;
  int wv   = threadIdx.x >> 6;

  if (inBF) {
    int t = threadIdx.x;
    if (t < 128) {
      ls_scale[t] = lsbuf[t];
      ls_shift[t] = lsbuf[128 + t];
    }
    __syncthreads();
  }

  int row0 = blockIdx.x * 64 + wv * 16;
  int gidx = lane & 15;
  int quad = lane >> 4;
  int rA   = row0 + gidx;
  int rAc  = rA < N_NODES ? rA : N_NODES - 1;
  int koff = quad * 8;

  f32x4 acc[9] = {};
#pragma unroll
  for (int ks = 0; ks < 4; ++ks) {
    int cb = ks * 32 + koff;
    float xv[8];
    if (inBF) {
      const uint4* xr = (const uint4*)((const unsigned*)Xin + (size_t)rAc * 64 + (cb >> 1));
      uint4 xa = *xr;
      xv[0] = bflo(xa.x); xv[1] = bfhi(xa.x);
      xv[2] = bflo(xa.y); xv[3] = bfhi(xa.y);
      xv[4] = bflo(xa.z); xv[5] = bfhi(xa.z);
      xv[6] = bflo(xa.w); xv[7] = bfhi(xa.w);
    } else {
      const float4* xr = (const float4*)((const float*)Xin + (size_t)rAc * FDIM + cb);
      float4 xa = xr[0], xb = xr[1];
      xv[0] = xa.x; xv[1] = xa.y; xv[2] = xa.z; xv[3] = xa.w;
      xv[4] = xb.x; xv[5] = xb.y; xv[6] = xb.z; xv[7] = xb.w;
    }
    bf16x8 afrag;
    if (inBF) {
#pragma unroll
      for (int j = 0; j < 8; ++j) {
        int c = cb + j;
        float v = fmaf(xv[j], ls_scale[c], ls_shift[c]);
        v = v > 0.f ? v : 0.f;
        afrag[j] = (short)f2bf(v);
      }
    } else {
#pragma unroll
      for (int j = 0; j < 8; ++j) afrag[j] = (short)f2bf(xv[j]);
    }
#pragma unroll
    for (int t = 0; t < 9; ++t) {
      bf16x8 bfrag = *(const bf16x8*)(WrL + ((size_t)((t * 4 + ks) * 64 + lane)) * 8);
      acc[t] = __builtin_amdgcn_mfma_f32_16x16x32_bf16(afrag, bfrag, acc[t], 0, 0, 0);
    }
  }

  // ---- logit columns: lane (quad,gidx<4) holds al[row=quad*4+r][gidx] ----
  if (gidx < 4) {
    float* dp = (gidx < 2) ? als : ald;
    int hd = gidx & 1;
#pragma unroll
    for (int r = 0; r < 4; ++r) {
      int row = row0 + quad * 4 + r;
      if (row < N_NODES) dp[row * 2 + hd] = acc[8][r];
    }
  }

  // ---- bf16 H store via LDS transpose ----
#pragma unroll
  for (int t = 0; t < 8; ++t)
#pragma unroll
    for (int r = 0; r < 4; ++r)
      lds[wv][quad * 4 + r][t * 16 + gidx] = f2bf(acc[t][r]);
  __syncthreads();
#pragma unroll
  for (int it = 0; it < 4; ++it) {
    int rloc = it * 4 + quad;
    int row = row0 + rloc;
    if (row < N_NODES)
      *(u16x8*)(Hbf + (size_t)row * FDIM + gidx * 8) = *(u16x8*)&lds[wv][rloc][gidx * 8];
  }
}

// ---------------- fused softmax-aggregate (R10 form) -----------------------
// One wave per node. Lane owns channels 2l,2l+1; lanes 0-31 = head 0,
// 32-63 = head 1. exp2 logits (log2e baked into W*a), no max shift.
// 8-deep clamped register prefetch. mode 0: write Abf bf16-pair + BN sums
// into part[32][256]; mode 2: head-mean + b2 -> out fp32 [N,64].
__global__ __launch_bounds__(256) void fused_agg(const int* __restrict__ rowptr,
                                                 const int* __restrict__ csr_src,
                                                 const unsigned* __restrict__ H2,
                                                 const float* __restrict__ als,
                                                 const float* __restrict__ ald,
                                                 unsigned* __restrict__ Abf,
                                                 float* __restrict__ out,
                                                 const float* __restrict__ b2,
                                                 float* __restrict__ part,
                                                 int mode) {
  int lane = threadIdx.x & 63;
  bool hi = lane >= 32;
  int n = __builtin_amdgcn_readfirstlane((blockIdx.x * 256 + threadIdx.x) >> 6);
  int beg = rowptr[n], end = rowptr[n + 1];
  float2 adv = ((const float2*)ald)[n];
  float advh = hi ? adv.y : adv.x;

  int b0 = end - 8; if (b0 > beg) b0 = beg; if (b0 < 0) b0 = 0;
  int delta = beg - b0;
  int sa[8]; float2 aa[8]; unsigned ha[8];
#pragma unroll
  for (int i = 0; i < 8; ++i) sa[i] = csr_src[b0 + i];
#pragma unroll
  for (int i = 0; i < 8; ++i) {
    aa[i] = ((const float2*)als)[sa[i]];
    ha[i] = H2[(size_t)sa[i] * 64 + lane];
  }

  float l = 0.f, ox = 0.f, oy = 0.f;

#define STEP(i) { \
    float v_ = (hi ? aa[i].y : aa[i].x) + advh; \
    v_ = fmaxf(v_, SLOPE * v_); \
    float e_ = exp2f(v_); \
    l += e_; \
    ox = fmaf(e_, bflo(ha[i]), ox); \
    oy = fmaf(e_, bfhi(ha[i]), oy); }

  int j = beg;
  for (; j + 8 <= end; j += 8) {
    int pp = j + 8; if (pp > end - 8) pp = end - 8;   // end-8 >= beg here
    int sn[8]; float2 an[8]; unsigned hn[8];
#pragma unroll
    for (int i = 0; i < 8; ++i) sn[i] = csr_src[pp + i];
#pragma unroll
    for (int i = 0; i < 8; ++i) {
      an[i] = ((const float2*)als)[sn[i]];
      hn[i] = H2[(size_t)sn[i] * 64 + lane];
    }
    STEP(0); STEP(1); STEP(2); STEP(3); STEP(4); STEP(5); STEP(6); STEP(7);
    delta = j + 8 - pp;
#pragma unroll
    for (int i = 0; i < 8; ++i) { aa[i] = an[i]; ha[i] = hn[i]; }
  }
  int rem = end - j;
  int hik = delta + rem;
  if (0 >= delta && 0 < hik) STEP(0);
  if (1 >= delta && 1 < hik) STEP(1);
  if (2 >= delta && 2 < hik) STEP(2);
  if (3 >= delta && 3 < hik) STEP(3);
  if (4 >= delta && 4 < hik) STEP(4);
  if (5 >= delta && 5 < hik) STEP(5);
  if (6 >= delta && 6 < hik) STEP(6);
  if (7 >= delta && 7 < hik) STEP(7);
#undef STEP

  float inv = 1.f / (l + 1e-16f);
  ox *= inv; oy *= inv;

  if (mode == 0) {
    Abf[(size_t)n * 64 + lane] = packbf(ox, oy);
    __shared__ float sh[4][4][64];
    int wv = threadIdx.x >> 6;
    sh[wv][0][lane] = ox;
    sh[wv][1][lane] = oy;
    sh[wv][2][lane] = ox * ox;
    sh[wv][3][lane] = oy * oy;
    __syncthreads();
    if (threadIdx.x < 64) {
      int t = threadIdx.x;
      float a0 = 0.f, a1 = 0.f, a2 = 0.f, a3 = 0.f;
#pragma unroll
      for (int w = 0; w < 4; ++w) {
        a0 += sh[w][0][t]; a1 += sh[w][1][t];
        a2 += sh[w][2][t]; a3 += sh[w][3][t];
      }
      float* slot = part + (blockIdx.x & 31) * 256;
      atomicAdd(&slot[2 * t],           a0);
      atomicAdd(&slot[2 * t + 1],       a1);
      atomicAdd(&slot[128 + 2 * t],     a2);
      atomicAdd(&slot[128 + 2 * t + 1], a3);
    }
  } else {
    float px = __shfl_xor(ox, 32);
    float py = __shfl_xor(oy, 32);
    if (lane < 32) {
      int c = lane * 2;
      float2 outv = {0.5f * (ox + px) + b2[c], 0.5f * (oy + py) + b2[c + 1]};
      *(float2*)(out + (size_t)n * 64 + c) = outv;
    }
  }
}

extern "C" void kernel_launch(void* const* d_in, const int* in_sizes, int n_in,
                              void* d_out, int out_size, void* d_ws, size_t ws_size,
                              hipStream_t stream) {
  const float* x  = (const float*)d_in[0];
  const int*   ei = (const int*)d_in[1];
  const int* src = ei;
  const int* dst = ei + N_EDGES;

  const float* W[3]    = {(const float*)d_in[2],  (const float*)d_in[8],  (const float*)d_in[14]};
  const float* asrc[3] = {(const float*)d_in[3],  (const float*)d_in[9],  (const float*)d_in[15]};
  const float* adst[3] = {(const float*)d_in[4],  (const float*)d_in[10], (const float*)d_in[16]};
  const float* g[2]    = {(const float*)d_in[6],  (const float*)d_in[12]};
  const float* be[2]   = {(const float*)d_in[7],  (const float*)d_in[13]};
  const float* b2      = (const float*)d_in[17];

  // workspace (4-byte units, regions 16B-aligned).
  // counts and part adjacent -> ONE memset zeroes both.
  int*   counts   = (int*)d_ws;                  // 50048
  float* part     = (float*)(counts + 50048);    // 8192 (32x256 BN slots)
  int*   rowptr   = (int*)(part + 8192);         // 50048
  int*   partials = rowptr + 50048;              // 256
  int*   rank     = partials + 256;              // 850048
  int*   csr_src  = rank + 850048;               // 850048
  float* lsbuf    = (float*)(csr_src + 850048);  // 256 scale|shift
  float* als      = lsbuf + 256;                 // 100096
  float* ald      = als + 100096;                // 100096
  unsigned short* Wr  = (unsigned short*)(ald + 100096);   // 3*WSTRIDE u16
  unsigned short* Hbf = Wr + 3 * WSTRIDE + 128;            // pad to 16B align
  unsigned* Abf   = (unsigned*)(Hbf + (size_t)N_NODES * FDIM);

  // ---- setup: zero counts+part, hist+repack, scan, scatter ----
  hipMemsetAsync(counts, 0, (50048 + 8192) * sizeof(int), stream);
  build_pre<<<HIST_NB + RPK_NB, 256, 0, stream>>>(
      dst, counts, rank, W[0], W[1], W[2],
      asrc[0], asrc[1], asrc[2], adst[0], adst[1], adst[2], Wr);
  scan_blk<<<SCAN_NB, 256, 0, stream>>>(counts, rowptr, partials);
  scan_fin<<<SCAN_NB, 256, 0, stream>>>(rowptr, partials);
  scatter_pos<<<(ET + 255) / 256, 256, 0, stream>>>(src, dst, rowptr, rank, csr_src);

  const int gemm_grid = (N_NODES + 63) / 64;
  const int agg_grid  = N_NODES * 64 / 256;   // 12500, exact (one wave/node)

  for (int L = 0; L < 3; ++L) {
    const void* fin = (L == 0) ? (const void*)x : (const void*)Abf;
    int inBF = (L > 0);
    gemm_mfma<<<gemm_grid, 256, 0, stream>>>(fin, Wr + (size_t)L * WSTRIDE, lsbuf,
                                             Hbf, als, ald, inBF);
    fused_agg<<<agg_grid, 256, 0, stream>>>(rowptr, csr_src, (const unsigned*)Hbf,
                                            als, ald, Abf, (float*)d_out, b2, part,
                                            (L == 2) ? 2 : 0);
    if (L < 2)
      bn_fin<<<1, 128, 0, stream>>>(part, g[L], be[L], lsbuf);
  }
}